// Round 1
// baseline (6160.975 us; speedup 1.0000x reference)
//
#include <hip/hip_runtime.h>

// SNN with STDP: T=100 sequential steps, 3 kernels/step.
// State + transposed W + scratch all live in d_ws (re-initialized every call).
// Lateral inhibition applied lazily at the start of the next step.

#define T_STEPS 100
#define BATCH   256
#define IDIM    784
#define NDIM    1024

#define ALPHA      0.9f
#define BETA       0.8f
#define BETA_PLUS  0.9f
#define BETA_MINUS 0.9f
#define THRESH     1.0f
#define REF_TIME   5.0f
#define LAT        0.1f
#define BETA_THETA 0.99f
#define THETA_ADD  0.05f
#define LRB        ((float)(0.01 / 256.0))

// ---- workspace layout (offsets in floats) ----
#define OFF_SYN    0u
#define OFF_MEM    262144u
#define OFF_SPK    524288u
#define OFF_THETA  786432u
#define OFF_REF    1048576u
#define OFF_POST   1310720u
#define OFF_PRETR  1572864u            /* B*I = 200704 */
#define OFF_CNT    1773568u            /* int[128] spike count per step */
#define OFF_WIN    1773696u            /* int[256] argmax winner per sample */
#define ZERO_FLOATS 1773952u
#define OFF_WT     1773952u            /* transposed W [I][N] = 802816 */
#define OFF_D1T    2576768u            /* term1 buffer [I][N] = 802816 */
#define OFF_XBI    3379584u            /* ushort[I*64] per-pixel b-lists */
#define OFF_XBC    3404672u            /* int[I] list counts */
// total ≈ 3,405,456 floats ≈ 13.6 MB

// Ordered (deterministic, ascending-index) stream compaction across a 256-thread block.
__device__ __forceinline__ int ordered_compact(const float* src, int stride, int limit,
                                               int nchunks, unsigned short* lst, int cap,
                                               int* s_wc, int* s_base)
{
    const int tid = threadIdx.x, lane = tid & 63, w = tid >> 6;
    if (tid == 0) *s_base = 0;
    __syncthreads();
    for (int c = 0; c < nchunks; ++c) {
        int idx = c * 256 + tid;
        bool pred = (idx < limit) && (src[(size_t)idx * stride] > 0.0f);
        unsigned long long m = __ballot(pred);
        if (lane == 0) s_wc[w] = __popcll(m);
        __syncthreads();
        int base = *s_base;
#pragma unroll
        for (int w2 = 0; w2 < 4; ++w2)
            if (w2 < w) base += s_wc[w2];
        if (pred) {
            int pos = base + __popcll(m & ((1ull << lane) - 1ull));
            if (pos < cap) lst[pos] = (unsigned short)idx;
        }
        __syncthreads();
        if (tid == 0) *s_base += s_wc[0] + s_wc[1] + s_wc[2] + s_wc[3];
        __syncthreads();
    }
    int tot = *s_base;
    return tot < cap ? tot : cap;
}

__global__ void k_init(float* __restrict__ ws)
{
    size_t i = (size_t)blockIdx.x * 256 + threadIdx.x;
    size_t stride = (size_t)gridDim.x * 256;
    for (; i < ZERO_FLOATS; i += stride) ws[i] = 0.0f;
}

__global__ void k_transW(const float* __restrict__ W, float* __restrict__ ws)
{
    int idx = blockIdx.x * 256 + threadIdx.x;
    if (idx >= NDIM * IDIM) return;
    int n = idx / IDIM, i = idx - n * IDIM;
    ws[OFF_WT + (size_t)i * NDIM + n] = W[idx];   // coalesced read, scattered write (one-time)
}

// Forward step for all samples + pre_trace update + per-pixel x b-lists.
// blocks [0,256): one sample each. blocks [256,1040): one input pixel each (b-list build).
__global__ __launch_bounds__(256)
void k_fwd(const float* __restrict__ image, float* __restrict__ ws,
           float* __restrict__ out, int t)
{
    __shared__ int s_wc[4];
    __shared__ int s_base;
    __shared__ unsigned short s_lst[208];
    __shared__ float s_v[256];
    __shared__ int   s_i[256];
    __shared__ int   s_c[256];

    const int tid = threadIdx.x;
    int*  cnt = (int*)(ws + OFF_CNT);
    int*  win = (int*)(ws + OFF_WIN);

    if (blockIdx.x >= BATCH) {
        // build b-list for pixel i (used by k_t2 this step)
        int i = blockIdx.x - BATCH;
        unsigned short* xbI = (unsigned short*)(ws + OFF_XBI);
        int* xbC = (int*)(ws + OFF_XBC);
        const float* src = image + (size_t)t * BATCH * IDIM + i;
        int m = ordered_compact(src, IDIM, BATCH, 1, xbI + i * 64, 64, s_wc, &s_base);
        if (tid == 0) xbC[i] = m;
        return;
    }

    const int b = blockIdx.x;
    float* syn   = ws + OFF_SYN;
    float* mem   = ws + OFF_MEM;
    float* spk   = ws + OFF_SPK;
    float* theta = ws + OFF_THETA;
    float* ref   = ws + OFF_REF;
    float* post  = ws + OFF_POST;
    const float* WT = ws + OFF_WT;

    const float* x = image + ((size_t)t * BATCH + b) * IDIM;
    int m = ordered_compact(x, 1, IDIM, 4, s_lst, 208, s_wc, &s_base);

    // pre_trace = BETA_PLUS * pre_trace + x_t
    float* pre_tr = ws + OFF_PRETR + (size_t)b * IDIM;
    for (int i = tid; i < IDIM; i += 256)
        pre_tr[i] = BETA_PLUS * pre_tr[i] + x[i];

    // lazy lateral inhibition from previous step
    const int cprev = (t > 0) ? cnt[t - 1] : 0;
    const int wprev = win[b];

    // gather pre[b, n] = sum over active i of WT[i, n]
    float pre[4] = {0.f, 0.f, 0.f, 0.f};
    for (int k = 0; k < m; ++k) {
        const float* wrow = WT + (size_t)s_lst[k] * NDIM + tid;
#pragma unroll
        for (int q = 0; q < 4; ++q) pre[q] += wrow[q * 256];
    }

    float bv = -3.0e38f; int bi = 0; int sc = 0;
#pragma unroll
    for (int q = 0; q < 4; ++q) {
        int n = q * 256 + tid;
        size_t idx = (size_t)b * NDIM + n;
        float syn_v = syn[idx], mem_v = mem[idx], spk_v = spk[idx];
        float th_v = theta[idx], ref_v = ref[idx];
        if (cprev > 0 && n != wprev) syn_v = fmaxf(syn_v - LAT, 0.0f);  // prev step's inhibition
        float thr = THRESH + th_v;
        ref_v += spk_v * REF_TIME;
        float syn_n = ALPHA * syn_v + pre[q];
        float mem_n = BETA * mem_v + syn_n - spk_v * thr;
        float spk_n = (mem_n > thr) ? 1.0f : 0.0f;
        if (ref_v > 0.0f) { spk_n = 0.0f; mem_n = mem_v; syn_n = syn_v; }   // refractory freeze
        ref_v -= 1.0f;
        float th_n = BETA_THETA * th_v + THETA_ADD * spk_n;
        float po_n = BETA_MINUS * post[idx] + spk_n;
        syn[idx] = syn_n; mem[idx] = mem_n; spk[idx] = spk_n;
        theta[idx] = th_n; ref[idx] = ref_v; post[idx] = po_n;
        out[((size_t)t * BATCH + b) * NDIM + n] = mem_n;
        if (mem_n > bv) { bv = mem_n; bi = n; }   // n ascending per thread -> first max kept
        sc += (spk_n != 0.0f) ? 1 : 0;
    }

    // block argmax (first-index tie-break) + spike count
    s_v[tid] = bv; s_i[tid] = bi; s_c[tid] = sc;
    __syncthreads();
    for (int off = 128; off > 0; off >>= 1) {
        if (tid < off) {
            float v2 = s_v[tid + off]; int i2 = s_i[tid + off];
            if (v2 > s_v[tid] || (v2 == s_v[tid] && i2 < s_i[tid])) { s_v[tid] = v2; s_i[tid] = i2; }
            s_c[tid] += s_c[tid + off];
        }
        __syncthreads();
    }
    if (tid == 0) {
        win[b] = s_i[0];
        if (s_c[0] > 0) atomicAdd(&cnt[t], s_c[0]);
    }
}

// term1: D1T[i, n] = sum_b spk[b,n] * pre_trace[b,i]   (only when any spikes this step)
__global__ __launch_bounds__(256)
void k_t1(float* __restrict__ ws, int t)
{
    const int* cnt = (const int*)(ws + OFF_CNT);
    if (cnt[t] == 0) return;                       // uniform early-out; D1T unread in this case
    const int ntile = blockIdx.x & 63, chunk = blockIdx.x >> 6;
    const int n0 = ntile * 16;
    const int i = chunk * 196 + threadIdx.x;
    if (threadIdx.x >= 196) return;
    const float* spk    = ws + OFF_SPK;
    const float* pre_tr = ws + OFF_PRETR;
    float acc[16];
#pragma unroll
    for (int j = 0; j < 16; ++j) acc[j] = 0.0f;
    for (int b = 0; b < BATCH; ++b) {
        float s[16]; bool any = false;
#pragma unroll
        for (int j = 0; j < 16; ++j) { s[j] = spk[(size_t)b * NDIM + n0 + j]; any = any || (s[j] != 0.0f); }
        if (!any) continue;                        // uniform branch
        float pv = pre_tr[(size_t)b * IDIM + i];
#pragma unroll
        for (int j = 0; j < 16; ++j) acc[j] = fmaf(s[j], pv, acc[j]);
    }
    float* dst = ws + OFF_D1T + (size_t)i * NDIM + n0;
#pragma unroll
    for (int j = 0; j < 16; j += 4) {
        float4 v = {acc[j], acc[j + 1], acc[j + 2], acc[j + 3]};
        *(float4*)(dst + j) = v;
    }
}

// term2 + weight update: WT[i,n] = clip(WT + LRB*(D1T[i,n] - sum_{b in xb(i)} post[b,n]), 0, 1)
__global__ __launch_bounds__(256)
void k_t2(float* __restrict__ ws, int t)
{
    const int i = blockIdx.x, tid = threadIdx.x;
    const int* cnt = (const int*)(ws + OFF_CNT);
    const int* xbC = (const int*)(ws + OFF_XBC);
    const unsigned short* xbI = (const unsigned short*)(ws + OFF_XBI);
    const float* post = ws + OFF_POST;
    const float* d1t = ws + OFF_D1T + (size_t)i * NDIM;
    float* wt = ws + OFF_WT + (size_t)i * NDIM;
    const int m = xbC[i];
    float acc[4] = {0.f, 0.f, 0.f, 0.f};
    for (int k = 0; k < m; ++k) {
        int b = xbI[i * 64 + k];
        const float* pr = post + (size_t)b * NDIM + tid;
#pragma unroll
        for (int q = 0; q < 4; ++q) acc[q] += pr[q * 256];
    }
    const bool has1 = cnt[t] > 0;
#pragma unroll
    for (int q = 0; q < 4; ++q) {
        int n = q * 256 + tid;
        float d1 = has1 ? d1t[n] : 0.0f;
        float w = wt[n] + LRB * (d1 - acc[q]);
        wt[n] = fminf(fmaxf(w, 0.0f), 1.0f);
    }
}

extern "C" void kernel_launch(void* const* d_in, const int* in_sizes, int n_in,
                              void* d_out, int out_size, void* d_ws, size_t ws_size,
                              hipStream_t stream)
{
    const float* image = (const float*)d_in[0];   // [T, B, I] binary spikes (fp32)
    const float* W     = (const float*)d_in[1];   // [N, I] fp32
    float* out = (float*)d_out;                   // [T, B, N] fp32
    float* ws  = (float*)d_ws;

    k_init<<<2048, 256, 0, stream>>>(ws);
    k_transW<<<(NDIM * IDIM + 255) / 256, 256, 0, stream>>>(W, ws);
    for (int t = 0; t < T_STEPS; ++t) {
        k_fwd<<<BATCH + IDIM, 256, 0, stream>>>(image, ws, out, t);
        k_t1<<<256, 256, 0, stream>>>(ws, t);
        k_t2<<<IDIM, 256, 0, stream>>>(ws, t);
    }
}

// Round 2
// 5637.159 us; speedup vs baseline: 1.0929x; 1.0929x over previous
//
#include <hip/hip_runtime.h>

// SNN with STDP: T=100 sequential steps, 3 kernels/step.
// Round 2: k_fwd widened to 1024 threads (4 waves/SIMD) to hide the L2 gather
// latency; per-pixel b-lists built inside k_t2; unrolled gathers.

#define T_STEPS 100
#define BATCH   256
#define IDIM    784
#define NDIM    1024

#define ALPHA      0.9f
#define BETA       0.8f
#define BETA_PLUS  0.9f
#define BETA_MINUS 0.9f
#define THRESH     1.0f
#define REF_TIME   5.0f
#define LAT        0.1f
#define BETA_THETA 0.99f
#define THETA_ADD  0.05f
#define LRB        ((float)(0.01 / 256.0))

// ---- workspace layout (offsets in floats) ----
#define OFF_SYN    0u
#define OFF_MEM    262144u
#define OFF_SPK    524288u
#define OFF_THETA  786432u
#define OFF_REF    1048576u
#define OFF_POST   1310720u
#define OFF_PRETR  1572864u            /* B*I = 200704 */
#define OFF_CNT    1773568u            /* int[128] spike count per step */
#define OFF_WIN    1773696u            /* int[256] argmax winner per sample */
#define ZERO_FLOATS 1773952u
#define OFF_WT     1773952u            /* transposed W [I][N] = 802816 */
#define OFF_D1T    2576768u            /* term1 buffer [I][N] = 802816 */
// total ≈ 3,379,584 floats ≈ 13.5 MB

__global__ void k_init(float* __restrict__ ws)
{
    size_t i = (size_t)blockIdx.x * 256 + threadIdx.x;
    size_t stride = (size_t)gridDim.x * 256;
    for (; i < ZERO_FLOATS; i += stride) ws[i] = 0.0f;
}

__global__ void k_transW(const float* __restrict__ W, float* __restrict__ ws)
{
    int idx = blockIdx.x * 256 + threadIdx.x;
    if (idx >= NDIM * IDIM) return;
    int n = idx / IDIM, i = idx - n * IDIM;
    ws[OFF_WT + (size_t)i * NDIM + n] = W[idx];   // coalesced read, scattered write (one-time)
}

// Forward step: one block per sample, one thread per neuron n.
__global__ __launch_bounds__(1024)
void k_fwd(const float* __restrict__ image, float* __restrict__ ws,
           float* __restrict__ out, int t)
{
    __shared__ unsigned short s_lst[208];
    __shared__ int s_wc[16];
    __shared__ int s_tot;
    __shared__ float s_v[1024];
    __shared__ int   s_i[1024];
    __shared__ int   s_c[1024];

    const int tid = threadIdx.x, lane = tid & 63, w = tid >> 6;
    const int b = blockIdx.x;
    int* cnt = (int*)(ws + OFF_CNT);
    int* win = (int*)(ws + OFF_WIN);

    // ---- ordered compaction of this sample's active inputs (ascending i) ----
    const float* x = image + ((size_t)t * BATCH + b) * IDIM;
    float xv = (tid < IDIM) ? x[tid] : 0.0f;
    bool pred = xv > 0.0f;
    unsigned long long mb = __ballot(pred);
    if (lane == 0) s_wc[w] = __popcll(mb);
    __syncthreads();
    int base = 0;
#pragma unroll
    for (int w2 = 0; w2 < 16; ++w2) base += (w2 < w) ? s_wc[w2] : 0;
    if (pred) {
        int pos = base + __popcll(mb & ((1ull << lane) - 1ull));
        if (pos < 208) s_lst[pos] = (unsigned short)tid;
    }
    if (tid == 0) {
        int tot = 0;
#pragma unroll
        for (int w2 = 0; w2 < 16; ++w2) tot += s_wc[w2];
        s_tot = tot;
    }
    // pre_trace = BETA_PLUS * pre_trace + x_t (independent of compaction)
    float* pre_tr = ws + OFF_PRETR + (size_t)b * IDIM;
    if (tid < IDIM) pre_tr[tid] = BETA_PLUS * pre_tr[tid] + xv;
    __syncthreads();
    int m = s_tot; if (m > 208) m = 208;

    const int cprev = (t > 0) ? cnt[t - 1] : 0;
    const int wprev = win[b];

    // ---- gather pre[n] = sum over active i of WT[i, n], ascending i ----
    const float* WTb = ws + OFF_WT + tid;
    float pre = 0.0f;
    int k = 0;
    for (; k + 4 <= m; k += 4) {
        int i0 = s_lst[k], i1 = s_lst[k + 1], i2 = s_lst[k + 2], i3 = s_lst[k + 3];
        float a0 = WTb[(size_t)i0 * NDIM];
        float a1 = WTb[(size_t)i1 * NDIM];
        float a2 = WTb[(size_t)i2 * NDIM];
        float a3 = WTb[(size_t)i3 * NDIM];
        pre += a0; pre += a1; pre += a2; pre += a3;
    }
    for (; k < m; ++k) pre += WTb[(size_t)s_lst[k] * NDIM];

    // ---- state update for n = tid ----
    float* syn   = ws + OFF_SYN;
    float* mem   = ws + OFF_MEM;
    float* spk   = ws + OFF_SPK;
    float* theta = ws + OFF_THETA;
    float* ref   = ws + OFF_REF;
    float* post  = ws + OFF_POST;

    size_t idx = (size_t)b * NDIM + tid;
    float syn_v = syn[idx], mem_v = mem[idx], spk_v = spk[idx];
    float th_v = theta[idx], ref_v = ref[idx];
    if (cprev > 0 && tid != wprev) syn_v = fmaxf(syn_v - LAT, 0.0f);  // lazy prev-step inhibition
    float thr = THRESH + th_v;
    ref_v += spk_v * REF_TIME;
    float syn_n = ALPHA * syn_v + pre;
    float mem_n = BETA * mem_v + syn_n - spk_v * thr;
    float spk_n = (mem_n > thr) ? 1.0f : 0.0f;
    if (ref_v > 0.0f) { spk_n = 0.0f; mem_n = mem_v; syn_n = syn_v; }   // refractory freeze
    ref_v -= 1.0f;
    theta[idx] = BETA_THETA * th_v + THETA_ADD * spk_n;
    post[idx]  = BETA_MINUS * post[idx] + spk_n;
    syn[idx] = syn_n; mem[idx] = mem_n; spk[idx] = spk_n; ref[idx] = ref_v;
    out[((size_t)t * BATCH + b) * NDIM + tid] = mem_n;

    // ---- block argmax (first-index tie-break) + spike count ----
    s_v[tid] = mem_n; s_i[tid] = tid; s_c[tid] = (spk_n != 0.0f) ? 1 : 0;
    __syncthreads();
    for (int off = 512; off > 0; off >>= 1) {
        if (tid < off) {
            float v2 = s_v[tid + off]; int i2 = s_i[tid + off];
            if (v2 > s_v[tid] || (v2 == s_v[tid] && i2 < s_i[tid])) { s_v[tid] = v2; s_i[tid] = i2; }
            s_c[tid] += s_c[tid + off];
        }
        __syncthreads();
    }
    if (tid == 0) {
        win[b] = s_i[0];
        if (s_c[0] > 0) atomicAdd(&cnt[t], s_c[0]);
    }
}

// term1: D1T[i, n] = sum_b spk[b,n] * pre_trace[b,i]   (only when any spikes this step)
__global__ __launch_bounds__(256)
void k_t1(float* __restrict__ ws, int t)
{
    const int* cnt = (const int*)(ws + OFF_CNT);
    if (cnt[t] == 0) return;                       // uniform early-out; D1T unread in this case
    const int ntile = blockIdx.x & 63, chunk = blockIdx.x >> 6;
    const int n0 = ntile * 16;
    const int i = chunk * 196 + threadIdx.x;
    if (threadIdx.x >= 196) return;
    const float* spk    = ws + OFF_SPK;
    const float* pre_tr = ws + OFF_PRETR;
    float acc[16];
#pragma unroll
    for (int j = 0; j < 16; ++j) acc[j] = 0.0f;
    for (int b = 0; b < BATCH; ++b) {
        float s[16]; bool any = false;
#pragma unroll
        for (int j = 0; j < 16; ++j) { s[j] = spk[(size_t)b * NDIM + n0 + j]; any = any || (s[j] != 0.0f); }
        if (!any) continue;                        // uniform branch
        float pv = pre_tr[(size_t)b * IDIM + i];
#pragma unroll
        for (int j = 0; j < 16; ++j) acc[j] = fmaf(s[j], pv, acc[j]);
    }
    float* dst = ws + OFF_D1T + (size_t)i * NDIM + n0;
#pragma unroll
    for (int j = 0; j < 16; j += 4) {
        float4 v = {acc[j], acc[j + 1], acc[j + 2], acc[j + 3]};
        *(float4*)(dst + j) = v;
    }
}

// term2 + weight update: WT[i,n] = clip(WT + LRB*(D1T[i,n] - sum_{b in xb(i)} post[b,n]), 0, 1)
// b-list for pixel i built in-block (ordered ballot over the 256 samples).
__global__ __launch_bounds__(256)
void k_t2(const float* __restrict__ image, float* __restrict__ ws, int t)
{
    __shared__ unsigned short s_lst[64];
    __shared__ int s_wc[4];
    __shared__ int s_tot;

    const int i = blockIdx.x, tid = threadIdx.x, lane = tid & 63, w = tid >> 6;

    // build b-list: samples with x[t, b, i] > 0, ascending b
    bool pred = image[((size_t)t * BATCH + tid) * IDIM + i] > 0.0f;
    unsigned long long mb = __ballot(pred);
    if (lane == 0) s_wc[w] = __popcll(mb);
    __syncthreads();
    int base = 0;
#pragma unroll
    for (int w2 = 0; w2 < 4; ++w2) base += (w2 < w) ? s_wc[w2] : 0;
    if (pred) {
        int pos = base + __popcll(mb & ((1ull << lane) - 1ull));
        if (pos < 64) s_lst[pos] = (unsigned short)tid;
    }
    if (tid == 0) s_tot = s_wc[0] + s_wc[1] + s_wc[2] + s_wc[3];
    __syncthreads();
    int m = s_tot; if (m > 64) m = 64;

    const int* cnt = (const int*)(ws + OFF_CNT);
    const float* post = ws + OFF_POST;
    const float* d1t = ws + OFF_D1T + (size_t)i * NDIM;
    float* wt = ws + OFF_WT + (size_t)i * NDIM;

    float acc[4] = {0.f, 0.f, 0.f, 0.f};
    int k = 0;
    for (; k + 2 <= m; k += 2) {
        const float* p0 = post + (size_t)s_lst[k] * NDIM + tid;
        const float* p1 = post + (size_t)s_lst[k + 1] * NDIM + tid;
        float b0[4], b1[4];
#pragma unroll
        for (int q = 0; q < 4; ++q) { b0[q] = p0[q * 256]; b1[q] = p1[q * 256]; }
#pragma unroll
        for (int q = 0; q < 4; ++q) { acc[q] += b0[q]; acc[q] += b1[q]; }
    }
    for (; k < m; ++k) {
        const float* pr = post + (size_t)s_lst[k] * NDIM + tid;
#pragma unroll
        for (int q = 0; q < 4; ++q) acc[q] += pr[q * 256];
    }

    const bool has1 = cnt[t] > 0;
#pragma unroll
    for (int q = 0; q < 4; ++q) {
        int n = q * 256 + tid;
        float d1 = has1 ? d1t[n] : 0.0f;
        float wv = wt[n] + LRB * (d1 - acc[q]);
        wt[n] = fminf(fmaxf(wv, 0.0f), 1.0f);
    }
}

extern "C" void kernel_launch(void* const* d_in, const int* in_sizes, int n_in,
                              void* d_out, int out_size, void* d_ws, size_t ws_size,
                              hipStream_t stream)
{
    const float* image = (const float*)d_in[0];   // [T, B, I] binary spikes (fp32)
    const float* W     = (const float*)d_in[1];   // [N, I] fp32
    float* out = (float*)d_out;                   // [T, B, N] fp32
    float* ws  = (float*)d_ws;

    k_init<<<2048, 256, 0, stream>>>(ws);
    k_transW<<<(NDIM * IDIM + 255) / 256, 256, 0, stream>>>(W, ws);
    for (int t = 0; t < T_STEPS; ++t) {
        k_fwd<<<BATCH, 1024, 0, stream>>>(image, ws, out, t);
        k_t1<<<256, 256, 0, stream>>>(ws, t);
        k_t2<<<IDIM, 256, 0, stream>>>(image, ws, t);
    }
}